// Round 4
// baseline (364.779 us; speedup 1.0000x reference)
//
#include <hip/hip_runtime.h>

typedef __attribute__((ext_vector_type(8))) __bf16 bf16x8;
typedef __attribute__((ext_vector_type(4))) float f32x4;
typedef __attribute__((ext_vector_type(16))) float f32x16;
typedef __attribute__((ext_vector_type(8))) unsigned short ushort8;
typedef __attribute__((ext_vector_type(4))) unsigned short u16x4;

#define DSAMP 512
#define DIM   128
#define ROWB  144                    // padded row pitch: 64 bf16 = 128 B + 16 B
#define S1    ((size_t)18874368)     // one hi or lo array: 128 b * 2 c * 512 r * 144 B
#define REG4  36864                  // one staged region: 256 rows * 144 B
#define WS_NEEDED ((size_t)(4 * S1 + 2 * 262144 + 6144 * 4))

// ---------------------------------------------------------------------------
// Pass 1: coalesced flat loads -> register Dekker split -> padded LDS images ->
// linear coalesced b128 copy-out. Block = 64 rows of one input. (unchanged)
// ---------------------------------------------------------------------------
__global__ __launch_bounds__(256)
void presplit2(const float* __restrict__ x, const float* __restrict__ y,
               char* __restrict__ ws) {
    __shared__ __align__(16) char img[4 * 9216];   // [hl*2+chunk]: 64 rows x 144 B
    __shared__ float nrm[64];

    const int tid = threadIdx.x;
    const int nb  = gridDim.x >> 1;
    const int input = (blockIdx.x >= nb) ? 1 : 0;
    const int rb    = blockIdx.x - input * nb;      // 64-row group index

    const float* src = (input ? y : x) + (size_t)rb * 64 * DIM;

    #pragma unroll
    for (int i = 0; i < 8; ++i) {
        int f  = i * 256 + tid;        // flat float4 index, 0..2047 (coalesced)
        int r  = f >> 5;               // row 0..63
        int k4 = f & 31;               // float4 within row
        float4 v = ((const float4*)src)[f];

        float s = v.x * v.x + v.y * v.y + v.z * v.z + v.w * v.w;
        #pragma unroll
        for (int o = 16; o > 0; o >>= 1) s += __shfl_down(s, o, 32);
        if ((tid & 31) == 0) nrm[r] = s;

        float xs[4] = {v.x, v.y, v.z, v.w};
        u16x4 hv, lv;
        #pragma unroll
        for (int e = 0; e < 4; ++e) {
            float xv = xs[e];
            unsigned ub = __float_as_uint(xv);
            unsigned hr = (ub + 0x7fffu + ((ub >> 16) & 1u)) >> 16;
            float hf = __uint_as_float(hr << 16);
            float rs = xv - hf;                      // exact residual (Dekker)
            unsigned ul = __float_as_uint(rs);
            unsigned lr = (ul + 0x7fffu + ((ul >> 16) & 1u)) >> 16;
            hv[e] = (unsigned short)hr;
            lv[e] = (unsigned short)lr;
        }
        int c    = k4 >> 4;
        int col8 = (k4 & 15) * 8;
        *(u16x4*)(img + (size_t)(0 + c) * 9216 + r * ROWB + col8) = hv;
        *(u16x4*)(img + (size_t)(2 + c) * 9216 + r * ROWB + col8) = lv;
    }
    __syncthreads();

    const int wv = tid >> 6, lane = tid & 63;
    const int hl = wv >> 1, ch = wv & 1;
    const int b     = rb >> 3;
    const int rowin = (rb & 7) * 64;
    char* gdst = ws + (size_t)input * 2 * S1 + (size_t)hl * S1
               + ((size_t)(b * 2 + ch) * 512 + rowin) * ROWB;
    const char* lsrc = img + (size_t)wv * 9216;
    #pragma unroll
    for (int j = 0; j < 9; ++j) {
        int o = (j * 64 + lane) * 16;
        *(float4*)(gdst + o) = *(const float4*)(lsrc + o);
    }
    if (tid < 64) {
        float* nG = (float*)(ws + 4 * S1) + (size_t)input * 65536 + rb * 64;
        nG[tid] = nrm[tid];
    }
}

// ---------------------------------------------------------------------------
// Pass 2 v4: 256x256 tile per block, 4 waves of 128x128 (4x4 tiles of
// 32x32x16 bf16, 2-term hh + h*lo). 10 blocks/batch (upper-tri for xx/yy).
// ---------------------------------------------------------------------------
__global__ __launch_bounds__(256, 1)
void mmd_tile4(const char* __restrict__ ws, float* __restrict__ partials) {
    __shared__ __align__(16) char smem[3 * REG4];   // Ah, Bh, Bl (110592 B)
    __shared__ float Pn[256];
    __shared__ float Qn[256];
    __shared__ float wred[4];

    const int tid = threadIdx.x;
    const int bid = blockIdx.x;
    const int b   = bid / 10;
    const int s   = bid - b * 10;

    // block table: type (0 xy, 1 xx, 2 yy), tile coords at 256-granularity, weight
    int type, ti, tj; float w; bool diag;
    if (s < 4)      { type = 0; ti = s >> 1; tj = s & 1; w = 1.0f;  diag = false; }
    else if (s < 7) { type = 1; int u = s - 4; ti = (u >> 1); tj = (u + 1) >> 1;   // (0,0),(0,1),(1,1)
                      w = (u == 1) ? -1.0f : -0.5f; diag = (u != 1); }
    else            { type = 2; int u = s - 7; ti = (u >> 1); tj = (u + 1) >> 1;
                      w = (u == 1) ? -1.0f : -0.5f; diag = (u != 1); }

    const char* Xhi = ws;
    const char* Yhi = ws + 2 * S1;
    const float* normX = (const float*)(ws + 4 * S1);
    const float* normY = normX + 65536;

    const char* Phi; const char* Qhi; const float* nP; const float* nQ;
    if (type == 0)      { Phi = Xhi; Qhi = Yhi; nP = normX; nQ = normY; }
    else if (type == 1) { Phi = Xhi; Qhi = Xhi; nP = normX; nQ = normX; }
    else                { Phi = Yhi; Qhi = Yhi; nP = normY; nQ = normY; }

    Pn[tid] = nP[(size_t)b * 512 + ti * 256 + tid];
    Qn[tid] = nQ[(size_t)b * 512 + tj * 256 + tid];

    const int lane    = tid & 63;
    const int wv      = tid >> 6;
    const int rowBase = (wv >> 1) * 128;   // within 256-row block
    const int colBase = (wv & 1) * 128;
    const int cl      = lane & 31;
    const int hf      = lane >> 5;

    f32x16 acc[4][4];
    #pragma unroll
    for (int a2 = 0; a2 < 4; ++a2)
        #pragma unroll
        for (int b2 = 0; b2 < 4; ++b2)
            #pragma unroll
            for (int r = 0; r < 16; ++r)
                acc[a2][b2][r] = 0.f;

    for (int c = 0; c < 2; ++c) {
        if (c) __syncthreads();
        // stage 3 regions x 36864 B = 108 DMA instrs, 27 per wave
        {
            size_t chrow = (size_t)(b * 2 + c) * 512;
            const char* src0 = Phi + (chrow + (size_t)ti * 256) * ROWB;
            const char* src1 = Qhi + (chrow + (size_t)tj * 256) * ROWB;
            const char* src2 = src1 + S1;   // Q-lo mirrors Q-hi at +S1
            #pragma unroll
            for (int f = 0; f < 27; ++f) {
                int g = wv * 27 + f;
                int region = g / 36;
                int sub    = g - region * 36;
                const char* gs = (region == 0 ? src0 : (region == 1 ? src1 : src2))
                               + sub * 1024 + lane * 16;
                char* ls = smem + (size_t)region * REG4 + sub * 1024 + lane * 16;
                __builtin_amdgcn_global_load_lds(
                    (const __attribute__((address_space(1))) void*)gs,
                    (__attribute__((address_space(3))) void*)ls, 16, 0, 0);
            }
        }
        __syncthreads();
        // compute: 4 k16-steps over this 64-wide chunk
        #pragma unroll
        for (int kt = 0; kt < 4; ++kt) {
            const int ko = kt * 32 + hf * 16;   // byte offset within 128-B row data
            bf16x8 ah[4], bh[4], bl[4];
            #pragma unroll
            for (int a2 = 0; a2 < 4; ++a2)
                ah[a2] = *(const bf16x8*)(smem + (rowBase + a2 * 32 + cl) * ROWB + ko);
            #pragma unroll
            for (int b2 = 0; b2 < 4; ++b2) {
                bh[b2] = *(const bf16x8*)(smem + REG4     + (colBase + b2 * 32 + cl) * ROWB + ko);
                bl[b2] = *(const bf16x8*)(smem + 2 * REG4 + (colBase + b2 * 32 + cl) * ROWB + ko);
            }
            #pragma unroll
            for (int a2 = 0; a2 < 4; ++a2)
                #pragma unroll
                for (int b2 = 0; b2 < 4; ++b2) {
                    acc[a2][b2] = __builtin_amdgcn_mfma_f32_32x32x16_bf16(ah[a2], bh[b2], acc[a2][b2], 0, 0, 0);
                    acc[a2][b2] = __builtin_amdgcn_mfma_f32_32x32x16_bf16(ah[a2], bl[b2], acc[a2][b2], 0, 0, 0);
                }
        }
    }

    // ---- epilogue: d2 = Pn + Qn - 2g -> guarded sqrt -> reduce ----
    float Qc[4];
    #pragma unroll
    for (int b2 = 0; b2 < 4; ++b2) Qc[b2] = Qn[colBase + b2 * 32 + cl];

    float lsum = 0.f;
    #pragma unroll
    for (int a2 = 0; a2 < 4; ++a2) {
        #pragma unroll
        for (int r = 0; r < 16; ++r) {
            int row = rowBase + a2 * 32 + (r & 3) + 8 * (r >> 2) + 4 * hf;
            float pn = Pn[row];                    // broadcast within half-wave
            #pragma unroll
            for (int b2 = 0; b2 < 4; ++b2) {
                float d2 = fmaf(-2.0f, acc[a2][b2][r], pn + Qc[b2]);
                float v  = __builtin_amdgcn_sqrtf(fmaxf(d2, 0.0f));
                if (diag && row == (colBase + b2 * 32 + cl)) v = 0.f;
                lsum += v;
            }
        }
    }
    #pragma unroll
    for (int off = 32; off > 0; off >>= 1) lsum += __shfl_down(lsum, off, 64);
    if (lane == 0) wred[wv] = lsum;
    __syncthreads();
    if (tid == 0)
        partials[bid] = (wred[0] + wred[1] + wred[2] + wred[3]) * w;
}

// ---------------------------------------------------------------------------
// Fallback (in-kernel conversion) if ws_size is too small. (round-1 kernel)
// ---------------------------------------------------------------------------
__global__ __launch_bounds__(256, 2)
void mmd_tile_fallback(const float* __restrict__ x, const float* __restrict__ y,
                       float* __restrict__ partials) {
    __shared__ __align__(16) char smem[4 * 128 * ROWB];
    __shared__ float Pn[128];
    __shared__ float Qn[128];
    __shared__ float wred[4];

    char* Ah = smem;
    char* Al = smem + 1 * 128 * ROWB;
    char* Bh = smem + 2 * 128 * ROWB;
    char* Bl = smem + 3 * 128 * ROWB;

    const int tid  = threadIdx.x;
    const int bid  = blockIdx.x;
    const int tj   = bid & 3;
    const int ti   = (bid >> 2) & 3;
    const int type = (bid >> 4) % 3;
    const int b    = bid / 48;

    const float* Xb = x + (size_t)b * DSAMP * DIM;
    const float* Yb = y + (size_t)b * DSAMP * DIM;
    const float* Pp; const float* Qp; float w;
    if (type == 0)      { Pp = Xb; Qp = Yb; w = 1.0f;  }
    else if (type == 1) { Pp = Xb; Qp = Xb; w = -0.5f; }
    else                { Pp = Yb; Qp = Yb; w = -0.5f; }
    Pp += (size_t)ti * 128 * DIM;
    Qp += (size_t)tj * 128 * DIM;

    {
        const float* rp = (tid < 128) ? (Pp + (size_t)tid * DIM)
                                      : (Qp + (size_t)(tid - 128) * DIM);
        float s = 0.f;
        #pragma unroll
        for (int k4 = 0; k4 < 32; ++k4) {
            float4 v = ((const float4*)rp)[k4];
            s += v.x * v.x + v.y * v.y + v.z * v.z + v.w * v.w;
        }
        if (tid < 128) Pn[tid] = s; else Qn[tid - 128] = s;
    }

    const int lane    = tid & 63;
    const int wv      = tid >> 6;
    const int rowHalf = (wv >> 1) * 64;
    const int colHalf = (wv & 1) * 64;
    const int fm      = lane & 15;
    const int kq      = lane >> 4;

    f32x4 acc[4][4];
    #pragma unroll
    for (int a2 = 0; a2 < 4; ++a2)
        #pragma unroll
        for (int b2 = 0; b2 < 4; ++b2)
            acc[a2][b2] = (f32x4){0.f, 0.f, 0.f, 0.f};

    for (int c = 0; c < 2; ++c) {
        if (c) __syncthreads();
        #pragma unroll
        for (int side = 0; side < 2; ++side) {
            const float* sp = side ? Qp : Pp;
            char* dh = side ? Bh : Ah;
            char* dl = side ? Bl : Al;
            #pragma unroll
            for (int it = 0; it < 4; ++it) {
                int u  = it * 256 + tid;
                int r  = u >> 3;
                int c8 = u & 7;
                const float* g = sp + (size_t)r * DIM + c * 64 + c8 * 8;
                float4 v0 = ((const float4*)g)[0];
                float4 v1 = ((const float4*)g)[1];
                float xs[8] = {v0.x, v0.y, v0.z, v0.w, v1.x, v1.y, v1.z, v1.w};
                ushort8 hv, lv;
                #pragma unroll
                for (int e = 0; e < 8; ++e) {
                    float xv = xs[e];
                    unsigned ub = __float_as_uint(xv);
                    unsigned hr = (ub + 0x7fffu + ((ub >> 16) & 1u)) >> 16;
                    float hf = __uint_as_float(hr << 16);
                    float rs = xv - hf;
                    unsigned ul = __float_as_uint(rs);
                    unsigned lr = (ul + 0x7fffu + ((ul >> 16) & 1u)) >> 16;
                    hv[e] = (unsigned short)hr;
                    lv[e] = (unsigned short)lr;
                }
                *(ushort8*)(dh + r * ROWB + c8 * 16) = hv;
                *(ushort8*)(dl + r * ROWB + c8 * 16) = lv;
            }
        }
        __syncthreads();
        #pragma unroll
        for (int ks = 0; ks < 2; ++ks) {
            const int kb2 = (ks * 32 + kq * 8) * 2;
            bf16x8 ah[4], al[4], bh[4], bl[4];
            #pragma unroll
            for (int a2 = 0; a2 < 4; ++a2) {
                int ar = rowHalf + a2 * 16 + fm;
                ah[a2] = *(const bf16x8*)(Ah + ar * ROWB + kb2);
                al[a2] = *(const bf16x8*)(Al + ar * ROWB + kb2);
            }
            #pragma unroll
            for (int b2 = 0; b2 < 4; ++b2) {
                int br = colHalf + b2 * 16 + fm;
                bh[b2] = *(const bf16x8*)(Bh + br * ROWB + kb2);
                bl[b2] = *(const bf16x8*)(Bl + br * ROWB + kb2);
            }
            #pragma unroll
            for (int a2 = 0; a2 < 4; ++a2)
                #pragma unroll
                for (int b2 = 0; b2 < 4; ++b2) {
                    acc[a2][b2] = __builtin_amdgcn_mfma_f32_16x16x32_bf16(ah[a2], bh[b2], acc[a2][b2], 0, 0, 0);
                    acc[a2][b2] = __builtin_amdgcn_mfma_f32_16x16x32_bf16(ah[a2], bl[b2], acc[a2][b2], 0, 0, 0);
                    acc[a2][b2] = __builtin_amdgcn_mfma_f32_16x16x32_bf16(al[a2], bh[b2], acc[a2][b2], 0, 0, 0);
                }
        }
    }

    const bool selfm = (type != 0) && (ti == tj);
    float lsum = 0.f;
    #pragma unroll
    for (int a2 = 0; a2 < 4; ++a2) {
        int ib = rowHalf + a2 * 16 + kq * 4;
        #pragma unroll
        for (int b2 = 0; b2 < 4; ++b2) {
            int j = colHalf + b2 * 16 + fm;
            float qn = Qn[j];
            #pragma unroll
            for (int rg = 0; rg < 4; ++rg) {
                int i = ib + rg;
                float d2 = Pn[i] + qn - 2.0f * acc[a2][b2][rg];
                if (d2 > 0.f && !(selfm && i == j)) lsum += sqrtf(d2);
            }
        }
    }
    #pragma unroll
    for (int off = 32; off > 0; off >>= 1) lsum += __shfl_down(lsum, off, 64);
    if (lane == 0) wred[wv] = lsum;
    __syncthreads();
    if (tid == 0)
        partials[bid] = (wred[0] + wred[1] + wred[2] + wred[3]) * w;
}

__global__ __launch_bounds__(256)
void mmd_finalize_kernel(const float* __restrict__ partials, int n,
                         float* __restrict__ out, double scale) {
    __shared__ double sh[256];
    double s = 0.0;
    for (int i = threadIdx.x; i < n; i += 256) s += (double)partials[i];
    sh[threadIdx.x] = s;
    __syncthreads();
    for (int off = 128; off > 0; off >>= 1) {
        if ((int)threadIdx.x < off) sh[threadIdx.x] += sh[threadIdx.x + off];
        __syncthreads();
    }
    if (threadIdx.x == 0) out[0] = (float)(sh[0] * scale);
}

extern "C" void kernel_launch(void* const* d_in, const int* in_sizes, int n_in,
                              void* d_out, int out_size, void* d_ws, size_t ws_size,
                              hipStream_t stream) {
    const float* x = (const float*)d_in[0];
    const float* y = (const float*)d_in[1];
    float* out = (float*)d_out;

    const int n = in_sizes[0];
    const int B = n / (DSAMP * DIM);       // 128
    const double scale = 1.0 / ((double)B * (double)DSAMP * (double)DSAMP);

    if (ws_size >= WS_NEEDED) {
        char* ws = (char*)d_ws;
        float* partials = (float*)(ws + 4 * S1 + 2 * 262144);
        const int nb = (n / DIM) / 64;     // 1024: 64-row groups per input
        const int nblocks = B * 10;        // upper-tri: 4 xy + 3 xx + 3 yy
        presplit2<<<dim3(2 * nb), dim3(256), 0, stream>>>(x, y, ws);
        mmd_tile4<<<dim3(nblocks), dim3(256), 0, stream>>>(ws, partials);
        mmd_finalize_kernel<<<dim3(1), dim3(256), 0, stream>>>(partials, nblocks, out, scale);
    } else {
        float* partials = (float*)d_ws;
        const int nblocks = B * 48;
        mmd_tile_fallback<<<dim3(nblocks), dim3(256), 0, stream>>>(x, y, partials);
        mmd_finalize_kernel<<<dim3(1), dim3(256), 0, stream>>>(partials, nblocks, out, scale);
    }
}

// Round 5
// 153.257 us; speedup vs baseline: 2.3802x; 2.3802x over previous
//
#include <hip/hip_runtime.h>

typedef __attribute__((ext_vector_type(8))) __bf16 bf16x8;
typedef __attribute__((ext_vector_type(4))) float f32x4;
typedef __attribute__((ext_vector_type(8))) unsigned short ushort8;
typedef __attribute__((ext_vector_type(4))) unsigned short u16x4;

#define DSAMP 512
#define DIM   128
#define S1    ((size_t)16777216)   // one hi/lo array: 128 b * 2 c * 512 r * 128 B (swizzled, no pad)
#define REG5  16384                // one staged region: 128 rows * 128 B
#define NBPB  36                   // blocks per batch: 16 xy + 10 xx + 10 yy
#define WS_NEEDED ((size_t)(4 * S1 + 2 * 262144 + 128 * NBPB * 4))

// ---------------------------------------------------------------------------
// Pass 1 v3: coalesced loads -> register Dekker split -> XOR-swizzled 128B-pitch
// LDS images -> linear coalesced copy-out. Block = 64 rows of one input.
// Swizzle: 16B block j of row r stored at block (j ^ (r & 7)).
// ---------------------------------------------------------------------------
__global__ __launch_bounds__(256)
void presplit3(const float* __restrict__ x, const float* __restrict__ y,
               char* __restrict__ ws) {
    __shared__ __align__(16) char img[4 * 8192];   // [hl*2+chunk]: 64 rows x 128 B
    __shared__ float nrm[64];

    const int tid = threadIdx.x;
    const int nb  = gridDim.x >> 1;
    const int input = (blockIdx.x >= nb) ? 1 : 0;
    const int rb    = blockIdx.x - input * nb;      // 64-row group index

    const float* src = (input ? y : x) + (size_t)rb * 64 * DIM;

    #pragma unroll
    for (int i = 0; i < 8; ++i) {
        int f  = i * 256 + tid;        // flat float4 index, 0..2047 (coalesced)
        int r  = f >> 5;               // row 0..63
        int k4 = f & 31;               // float4 within row
        float4 v = ((const float4*)src)[f];

        float s = v.x * v.x + v.y * v.y + v.z * v.z + v.w * v.w;
        #pragma unroll
        for (int o = 16; o > 0; o >>= 1) s += __shfl_down(s, o, 32);
        if ((tid & 31) == 0) nrm[r] = s;

        float xs[4] = {v.x, v.y, v.z, v.w};
        u16x4 hv, lv;
        #pragma unroll
        for (int e = 0; e < 4; ++e) {
            float xv = xs[e];
            unsigned ub = __float_as_uint(xv);
            unsigned hr = (ub + 0x7fffu + ((ub >> 16) & 1u)) >> 16;
            float hf = __uint_as_float(hr << 16);
            float rs = xv - hf;                      // exact residual (Dekker)
            unsigned ul = __float_as_uint(rs);
            unsigned lr = (ul + 0x7fffu + ((ul >> 16) & 1u)) >> 16;
            hv[e] = (unsigned short)hr;
            lv[e] = (unsigned short)lr;
        }
        int c  = k4 >> 4;              // k-chunk 0/1
        int q  = k4 & 15;              // float4 within chunk
        int jb = q >> 1;               // 16B block 0..7
        int h  = q & 1;                // half within block
        int addr = r * 128 + ((jb ^ (r & 7)) * 16) + h * 8;
        *(u16x4*)(img + (size_t)(0 + c) * 8192 + addr) = hv;
        *(u16x4*)(img + (size_t)(2 + c) * 8192 + addr) = lv;
    }
    __syncthreads();

    // copy-out: wave wv owns image wv (hl = wv>>1, chunk = wv&1), linear b128
    const int wv = tid >> 6, lane = tid & 63;
    const int hl = wv >> 1, ch = wv & 1;
    const int b     = rb >> 3;
    const int rowin = (rb & 7) * 64;
    char* gdst = ws + (size_t)input * 2 * S1 + (size_t)hl * S1
               + ((size_t)(b * 2 + ch) * 512 + rowin) * 128;
    const char* lsrc = img + (size_t)wv * 8192;
    #pragma unroll
    for (int j = 0; j < 8; ++j) {
        int o = (j * 64 + lane) * 16;
        *(float4*)(gdst + o) = *(const float4*)(lsrc + o);
    }
    if (tid < 64) {
        float* nG = (float*)(ws + 4 * S1) + (size_t)input * 65536 + rb * 64;
        nG[tid] = nrm[tid];
    }
}

// ---------------------------------------------------------------------------
// Pass 2 v5: 128x128 tile, 4 waves of 64x64 (4x4 of 16x16x32, 2-term hh+h*lo),
// swizzled 48 KB LDS (3 blocks/CU), upper-triangle tiling (36 blocks/batch),
// XCD-aware block swizzle so each batch's data stays in one XCD's L2.
// ---------------------------------------------------------------------------
__global__ __launch_bounds__(256, 3)
void mmd_tile5(const char* __restrict__ ws, float* __restrict__ partials) {
    __shared__ __align__(16) char smem[3 * REG5];   // Ah, Bh, Bl (49152 B)
    __shared__ float Pn[128];
    __shared__ float Qn[128];
    __shared__ float wred[4];

    const int tid = threadIdx.x;
    // XCD swizzle: consecutive bids round-robin XCDs; give each XCD whole batches
    const int xcd = blockIdx.x & 7;
    const int seq = blockIdx.x >> 3;
    const int b   = xcd + 8 * (seq / NBPB);
    const int s   = seq % NBPB;

    int type, ti, tj; float w; bool diag;
    if (s < 16) { type = 0; ti = s >> 2; tj = s & 3; w = 1.0f; diag = false; }
    else {
        int u = s - 16;
        type = 1 + (u >= 10);
        if (u >= 10) u -= 10;
        int i = (u >= 4) + (u >= 7) + (u >= 9);
        int off = (i == 1) ? 4 : (i == 2) ? 7 : (i == 3) ? 9 : 0;
        int j = u - off + i;
        ti = i; tj = j; diag = (i == j); w = diag ? -0.5f : -1.0f;
    }

    const char* Xhi = ws;
    const char* Yhi = ws + 2 * S1;
    const float* normX = (const float*)(ws + 4 * S1);
    const float* normY = normX + 65536;

    const char* Phi = (type == 2) ? Yhi : Xhi;
    const char* Qhi = (type == 1) ? Xhi : Yhi;
    const float* nP = (type == 2) ? normY : normX;
    const float* nQ = (type == 1) ? normX : normY;

    if (tid < 128) Pn[tid]       = nP[(size_t)b * 512 + ti * 128 + tid];
    else           Qn[tid - 128] = nQ[(size_t)b * 512 + tj * 128 + (tid - 128)];

    const int lane    = tid & 63;
    const int wv      = tid >> 6;
    const int rowHalf = (wv >> 1) * 64;
    const int colHalf = (wv & 1) * 64;
    const int fm      = lane & 15;
    const int kq      = lane >> 4;
    const int sw      = fm & 7;        // row-swizzle key (row & 7 == fm & 7)

    f32x4 acc[4][4];
    #pragma unroll
    for (int a2 = 0; a2 < 4; ++a2)
        #pragma unroll
        for (int b2 = 0; b2 < 4; ++b2)
            acc[a2][b2] = (f32x4){0.f, 0.f, 0.f, 0.f};

    for (int c = 0; c < 2; ++c) {
        if (c) __syncthreads();
        // stage 3 regions x 16384 B = 48 DMA wave-instrs, 12 per wave
        {
            size_t chrow = (size_t)(b * 2 + c) * 512;
            const char* srcs[3];
            srcs[0] = Phi + (chrow + (size_t)ti * 128) * 128;
            srcs[1] = Qhi + (chrow + (size_t)tj * 128) * 128;
            srcs[2] = srcs[1] + S1;   // Q-lo mirrors Q-hi at +S1
            #pragma unroll
            for (int f = 0; f < 12; ++f) {
                int g = wv * 12 + f;           // 0..47
                int region = g >> 4;
                int sub    = g & 15;
                const char* gs = srcs[region] + sub * 1024 + lane * 16;
                char* ls = smem + (size_t)region * REG5 + sub * 1024 + lane * 16;
                __builtin_amdgcn_global_load_lds(
                    (const __attribute__((address_space(1))) void*)gs,
                    (__attribute__((address_space(3))) void*)ls, 16, 0, 0);
            }
        }
        __syncthreads();
        #pragma unroll
        for (int ks = 0; ks < 2; ++ks) {
            const int jx = ((ks * 4 + kq) ^ sw) * 16;   // swizzled 16B-block offset
            bf16x8 ah[4], bh[4], bl[4];
            #pragma unroll
            for (int a2 = 0; a2 < 4; ++a2) {
                int ar = rowHalf + a2 * 16 + fm;
                ah[a2] = *(const bf16x8*)(smem + ar * 128 + jx);
            }
            #pragma unroll
            for (int b2 = 0; b2 < 4; ++b2) {
                int br = colHalf + b2 * 16 + fm;
                bh[b2] = *(const bf16x8*)(smem + REG5     + br * 128 + jx);
                bl[b2] = *(const bf16x8*)(smem + 2 * REG5 + br * 128 + jx);
            }
            #pragma unroll
            for (int a2 = 0; a2 < 4; ++a2)
                #pragma unroll
                for (int b2 = 0; b2 < 4; ++b2) {
                    acc[a2][b2] = __builtin_amdgcn_mfma_f32_16x16x32_bf16(ah[a2], bh[b2], acc[a2][b2], 0, 0, 0);
                    acc[a2][b2] = __builtin_amdgcn_mfma_f32_16x16x32_bf16(ah[a2], bl[b2], acc[a2][b2], 0, 0, 0);
                }
        }
    }

    // ---- epilogue: d2 = Pn + Qn - 2g -> guarded sqrt -> reduce ----
    float Pr[16], Qc[4];
    #pragma unroll
    for (int a2 = 0; a2 < 4; ++a2)
        #pragma unroll
        for (int rg = 0; rg < 4; ++rg)
            Pr[a2 * 4 + rg] = Pn[rowHalf + a2 * 16 + kq * 4 + rg];
    #pragma unroll
    for (int b2 = 0; b2 < 4; ++b2) Qc[b2] = Qn[colHalf + b2 * 16 + fm];

    float lsum = 0.f;
    #pragma unroll
    for (int a2 = 0; a2 < 4; ++a2) {
        #pragma unroll
        for (int b2 = 0; b2 < 4; ++b2) {
            #pragma unroll
            for (int rg = 0; rg < 4; ++rg) {
                float d2 = fmaf(-2.0f, acc[a2][b2][rg], Pr[a2 * 4 + rg] + Qc[b2]);
                float v  = __builtin_amdgcn_sqrtf(fmaxf(d2, 0.0f));
                if (diag && (rowHalf + a2 * 16 + kq * 4 + rg) == (colHalf + b2 * 16 + fm))
                    v = 0.f;
                lsum += v;
            }
        }
    }
    #pragma unroll
    for (int off = 32; off > 0; off >>= 1) lsum += __shfl_down(lsum, off, 64);
    if (lane == 0) wred[wv] = lsum;
    __syncthreads();
    if (tid == 0)
        partials[blockIdx.x] = (wred[0] + wred[1] + wred[2] + wred[3]) * w;
}

// ---------------------------------------------------------------------------
// Fallback (in-kernel conversion, full 48 tiles/batch) if ws_size too small.
// ---------------------------------------------------------------------------
__global__ __launch_bounds__(256, 2)
void mmd_tile_fallback(const float* __restrict__ x, const float* __restrict__ y,
                       float* __restrict__ partials) {
    __shared__ __align__(16) char smem[4 * 128 * 144];
    __shared__ float Pn[128];
    __shared__ float Qn[128];
    __shared__ float wred[4];

    char* Ah = smem;
    char* Al = smem + 1 * 128 * 144;
    char* Bh = smem + 2 * 128 * 144;
    char* Bl = smem + 3 * 128 * 144;

    const int tid  = threadIdx.x;
    const int bid  = blockIdx.x;
    const int tj   = bid & 3;
    const int ti   = (bid >> 2) & 3;
    const int type = (bid >> 4) % 3;
    const int b    = bid / 48;

    const float* Xb = x + (size_t)b * DSAMP * DIM;
    const float* Yb = y + (size_t)b * DSAMP * DIM;
    const float* Pp; const float* Qp; float w;
    if (type == 0)      { Pp = Xb; Qp = Yb; w = 1.0f;  }
    else if (type == 1) { Pp = Xb; Qp = Xb; w = -0.5f; }
    else                { Pp = Yb; Qp = Yb; w = -0.5f; }
    Pp += (size_t)ti * 128 * DIM;
    Qp += (size_t)tj * 128 * DIM;

    {
        const float* rp = (tid < 128) ? (Pp + (size_t)tid * DIM)
                                      : (Qp + (size_t)(tid - 128) * DIM);
        float s = 0.f;
        #pragma unroll
        for (int k4 = 0; k4 < 32; ++k4) {
            float4 v = ((const float4*)rp)[k4];
            s += v.x * v.x + v.y * v.y + v.z * v.z + v.w * v.w;
        }
        if (tid < 128) Pn[tid] = s; else Qn[tid - 128] = s;
    }

    const int lane    = tid & 63;
    const int wv      = tid >> 6;
    const int rowHalf = (wv >> 1) * 64;
    const int colHalf = (wv & 1) * 64;
    const int fm      = lane & 15;
    const int kq      = lane >> 4;

    f32x4 acc[4][4];
    #pragma unroll
    for (int a2 = 0; a2 < 4; ++a2)
        #pragma unroll
        for (int b2 = 0; b2 < 4; ++b2)
            acc[a2][b2] = (f32x4){0.f, 0.f, 0.f, 0.f};

    for (int c = 0; c < 2; ++c) {
        if (c) __syncthreads();
        #pragma unroll
        for (int side = 0; side < 2; ++side) {
            const float* sp = side ? Qp : Pp;
            char* dh = side ? Bh : Ah;
            char* dl = side ? Bl : Al;
            #pragma unroll
            for (int it = 0; it < 4; ++it) {
                int u  = it * 256 + tid;
                int r  = u >> 3;
                int c8 = u & 7;
                const float* g = sp + (size_t)r * DIM + c * 64 + c8 * 8;
                float4 v0 = ((const float4*)g)[0];
                float4 v1 = ((const float4*)g)[1];
                float xs[8] = {v0.x, v0.y, v0.z, v0.w, v1.x, v1.y, v1.z, v1.w};
                ushort8 hv, lv;
                #pragma unroll
                for (int e = 0; e < 8; ++e) {
                    float xv = xs[e];
                    unsigned ub = __float_as_uint(xv);
                    unsigned hr = (ub + 0x7fffu + ((ub >> 16) & 1u)) >> 16;
                    float hf = __uint_as_float(hr << 16);
                    float rs = xv - hf;
                    unsigned ul = __float_as_uint(rs);
                    unsigned lr = (ul + 0x7fffu + ((ul >> 16) & 1u)) >> 16;
                    hv[e] = (unsigned short)hr;
                    lv[e] = (unsigned short)lr;
                }
                *(ushort8*)(dh + r * 144 + c8 * 16) = hv;
                *(ushort8*)(dl + r * 144 + c8 * 16) = lv;
            }
        }
        __syncthreads();
        #pragma unroll
        for (int ks = 0; ks < 2; ++ks) {
            const int kb2 = (ks * 32 + kq * 8) * 2;
            bf16x8 ah[4], al[4], bh[4], bl[4];
            #pragma unroll
            for (int a2 = 0; a2 < 4; ++a2) {
                int ar = rowHalf + a2 * 16 + fm;
                ah[a2] = *(const bf16x8*)(Ah + ar * 144 + kb2);
                al[a2] = *(const bf16x8*)(Al + ar * 144 + kb2);
            }
            #pragma unroll
            for (int b2 = 0; b2 < 4; ++b2) {
                int br = colHalf + b2 * 16 + fm;
                bh[b2] = *(const bf16x8*)(Bh + br * 144 + kb2);
                bl[b2] = *(const bf16x8*)(Bl + br * 144 + kb2);
            }
            #pragma unroll
            for (int a2 = 0; a2 < 4; ++a2)
                #pragma unroll
                for (int b2 = 0; b2 < 4; ++b2) {
                    acc[a2][b2] = __builtin_amdgcn_mfma_f32_16x16x32_bf16(ah[a2], bh[b2], acc[a2][b2], 0, 0, 0);
                    acc[a2][b2] = __builtin_amdgcn_mfma_f32_16x16x32_bf16(ah[a2], bl[b2], acc[a2][b2], 0, 0, 0);
                    acc[a2][b2] = __builtin_amdgcn_mfma_f32_16x16x32_bf16(al[a2], bh[b2], acc[a2][b2], 0, 0, 0);
                }
        }
    }

    const bool selfm = (type != 0) && (ti == tj);
    float lsum = 0.f;
    #pragma unroll
    for (int a2 = 0; a2 < 4; ++a2) {
        int ib = rowHalf + a2 * 16 + kq * 4;
        #pragma unroll
        for (int b2 = 0; b2 < 4; ++b2) {
            int j = colHalf + b2 * 16 + fm;
            float qn = Qn[j];
            #pragma unroll
            for (int rg = 0; rg < 4; ++rg) {
                int i = ib + rg;
                float d2 = Pn[i] + qn - 2.0f * acc[a2][b2][rg];
                if (d2 > 0.f && !(selfm && i == j)) lsum += sqrtf(d2);
            }
        }
    }
    #pragma unroll
    for (int off = 32; off > 0; off >>= 1) lsum += __shfl_down(lsum, off, 64);
    if (lane == 0) wred[wv] = lsum;
    __syncthreads();
    if (tid == 0)
        partials[bid] = (wred[0] + wred[1] + wred[2] + wred[3]) * w;
}

__global__ __launch_bounds__(256)
void mmd_finalize_kernel(const float* __restrict__ partials, int n,
                         float* __restrict__ out, double scale) {
    __shared__ double sh[256];
    double s = 0.0;
    for (int i = threadIdx.x; i < n; i += 256) s += (double)partials[i];
    sh[threadIdx.x] = s;
    __syncthreads();
    for (int off = 128; off > 0; off >>= 1) {
        if ((int)threadIdx.x < off) sh[threadIdx.x] += sh[threadIdx.x + off];
        __syncthreads();
    }
    if (threadIdx.x == 0) out[0] = (float)(sh[0] * scale);
}

extern "C" void kernel_launch(void* const* d_in, const int* in_sizes, int n_in,
                              void* d_out, int out_size, void* d_ws, size_t ws_size,
                              hipStream_t stream) {
    const float* x = (const float*)d_in[0];
    const float* y = (const float*)d_in[1];
    float* out = (float*)d_out;

    const int n = in_sizes[0];
    const int B = n / (DSAMP * DIM);       // 128
    const double scale = 1.0 / ((double)B * (double)DSAMP * (double)DSAMP);

    if (ws_size >= WS_NEEDED) {
        char* ws = (char*)d_ws;
        float* partials = (float*)(ws + 4 * S1 + 2 * 262144);
        const int nb = (n / DIM) / 64;     // 1024: 64-row groups per input
        const int nblocks = B * NBPB;      // 4608
        presplit3<<<dim3(2 * nb), dim3(256), 0, stream>>>(x, y, ws);
        mmd_tile5<<<dim3(nblocks), dim3(256), 0, stream>>>(ws, partials);
        mmd_finalize_kernel<<<dim3(1), dim3(256), 0, stream>>>(partials, nblocks, out, scale);
    } else {
        float* partials = (float*)d_ws;
        const int nblocks = B * 48;
        mmd_tile_fallback<<<dim3(nblocks), dim3(256), 0, stream>>>(x, y, partials);
        mmd_finalize_kernel<<<dim3(1), dim3(256), 0, stream>>>(partials, nblocks, out, scale);
    }
}